// Round 1
// baseline (718.341 us; speedup 1.0000x reference)
//
#include <hip/hip_runtime.h>

// Problem constants: B=2, C=64, D=32, H=64, W=64, HW=4096, heads=8, head_dim=8
#define CSTR 131072   // channel stride = D*HW = 32*4096
#define BSTR 8388608  // batch stride = C*CSTR

using uint4v = __attribute__((ext_vector_type(4))) unsigned int;

__device__ __forceinline__ unsigned short f2bf(float f) {
    unsigned u = __float_as_uint(f);
    u += 0x7fff + ((u >> 16) & 1);   // RNE
    return (unsigned short)(u >> 16);
}
__device__ __forceinline__ unsigned pack2(float a, float b) {
    return (unsigned)f2bf(a) | ((unsigned)f2bf(b) << 16);
}
__device__ __forceinline__ float bflo(unsigned u) { return __uint_as_float(u << 16); }
__device__ __forceinline__ float bfhi(unsigned u) { return __uint_as_float(u & 0xffff0000u); }

// Block: 256 threads = 8 positions (p, lane-low for coalescing) x 32 depths (d).
// LDS: K,V staged as bf16, layout [p][d][64 chans] packed 2/dword, 16B column
// groups XOR-swizzled by p so wave reads (same d', 8 distinct p) span all banks.
__global__ __launch_bounds__(256, 2)
void attn_fused(const float* __restrict__ qf, const float* __restrict__ kf,
                const float* __restrict__ Wq, const float* __restrict__ Wk,
                const float* __restrict__ Wv, const float* __restrict__ Wo,
                float* __restrict__ out)
{
    __shared__ unsigned int kls[8192];  // [p][d][32 dwords] = 32 KB
    __shared__ unsigned int vls[8192];  // 32 KB  (total 64 KB -> 2 blocks/CU)

    const int tid = threadIdx.x;
    const int p   = tid & 7;
    const int d   = tid >> 3;
    const int bid = blockIdx.x;
    const int b   = bid >> 9;
    const int pg  = ((bid & 511) << 3) | p;

    const float* xkp = kf + b * BSTR + d * 4096 + pg;
    const float* xqp = qf + b * BSTR + d * 4096 + pg;

    // ---- Phase 1a: stream key column, compute K and V rows -> LDS (bf16) ----
    float xr[64];
    #pragma unroll
    for (int c = 0; c < 64; ++c) xr[c] = xkp[c * CSTR];

    const int base_dw = (p * 32 + d) * 32;
    #pragma unroll 1
    for (int g = 0; g < 8; ++g) {
        float ak[8], av[8];
        #pragma unroll
        for (int j = 0; j < 8; ++j) {
            const int o = g * 8 + j;
            float a0 = 0.f, a1 = 0.f;
            #pragma unroll
            for (int c = 0; c < 64; ++c) {
                a0 += Wk[o * 64 + c] * xr[c];
                a1 += Wv[o * 64 + c] * xr[c];
            }
            ak[j] = a0; av[j] = a1;
        }
        uint4v pk, pv;
        pk.x = pack2(ak[0], ak[1]); pk.y = pack2(ak[2], ak[3]);
        pk.z = pack2(ak[4], ak[5]); pk.w = pack2(ak[6], ak[7]);
        pv.x = pack2(av[0], av[1]); pv.y = pack2(av[2], av[3]);
        pv.z = pack2(av[4], av[5]); pv.w = pack2(av[6], av[7]);
        const int g2 = (g ^ p) * 4;
        *(uint4v*)&kls[base_dw + g2] = pk;
        *(uint4v*)&vls[base_dw + g2] = pv;
    }

    // ---- Phase 1b: stream query column into registers (kept live) ----
    #pragma unroll
    for (int c = 0; c < 64; ++c) xr[c] = xqp[c * CSTR];

    __syncthreads();

    // ---- Phase 2: per-head attention + Wo accumulation ----
    float outa[64];
    #pragma unroll
    for (int o = 0; o < 64; ++o) outa[o] = 0.f;

    const float scale = 0.35355339059327373f;  // 8^-0.5

    #pragma unroll 1
    for (int h = 0; h < 8; ++h) {
        // q for this head (recompute: same total FLOPs as precompute, keeps
        // register indexing static inside a rolled head loop)
        float qh[8];
        #pragma unroll
        for (int e = 0; e < 8; ++e) {
            float a = 0.f;
            #pragma unroll
            for (int c = 0; c < 64; ++c) a += Wq[(h * 8 + e) * 64 + c] * xr[c];
            qh[e] = a;
        }

        const int rb = p * 1024 + ((h ^ p) << 2);  // dword offset of this head's 16B group

        // scores s[d'] = scale * q . k_{d'}
        float s[32];
        #pragma unroll
        for (int dp = 0; dp < 32; ++dp) {
            const uint4v kk = *(const uint4v*)&kls[rb + dp * 32];
            float acc;
            acc  = qh[0] * bflo(kk.x);
            acc += qh[1] * bfhi(kk.x);
            acc += qh[2] * bflo(kk.y);
            acc += qh[3] * bfhi(kk.y);
            acc += qh[4] * bflo(kk.z);
            acc += qh[5] * bfhi(kk.z);
            acc += qh[6] * bflo(kk.w);
            acc += qh[7] * bfhi(kk.w);
            s[dp] = acc * scale;
        }

        // softmax over d'
        float m = s[0];
        #pragma unroll
        for (int dp = 1; dp < 32; ++dp) m = fmaxf(m, s[dp]);
        float sum = 0.f;
        #pragma unroll
        for (int dp = 0; dp < 32; ++dp) { s[dp] = __expf(s[dp] - m); sum += s[dp]; }
        const float inv = 1.0f / sum;

        // ctx = P . V
        float ctx[8];
        #pragma unroll
        for (int e = 0; e < 8; ++e) ctx[e] = 0.f;
        #pragma unroll
        for (int dp = 0; dp < 32; ++dp) {
            const uint4v vv = *(const uint4v*)&vls[rb + dp * 32];
            const float w = s[dp];
            ctx[0] += w * bflo(vv.x);
            ctx[1] += w * bfhi(vv.x);
            ctx[2] += w * bflo(vv.y);
            ctx[3] += w * bfhi(vv.y);
            ctx[4] += w * bflo(vv.z);
            ctx[5] += w * bfhi(vv.z);
            ctx[6] += w * bflo(vv.w);
            ctx[7] += w * bfhi(vv.w);
        }
        #pragma unroll
        for (int e = 0; e < 8; ++e) ctx[e] *= inv;

        // out[o] += Wo[o, 8h+e] * ctx[e]
        #pragma unroll
        for (int o = 0; o < 64; ++o) {
            float a = outa[o];
            #pragma unroll
            for (int e = 0; e < 8; ++e) a += Wo[o * 64 + h * 8 + e] * ctx[e];
            outa[o] = a;
        }
    }

    // ---- Epilogue: write out[b, o, d, pg] ----
    float* op = out + b * BSTR + d * 4096 + pg;
    #pragma unroll
    for (int o = 0; o < 64; ++o) op[o * CSTR] = outa[o];
}

extern "C" void kernel_launch(void* const* d_in, const int* in_sizes, int n_in,
                              void* d_out, int out_size, void* d_ws, size_t ws_size,
                              hipStream_t stream) {
    const float* qf = (const float*)d_in[0];
    const float* kf = (const float*)d_in[1];
    const float* Wq = (const float*)d_in[2];
    const float* Wk = (const float*)d_in[3];
    const float* Wv = (const float*)d_in[4];
    const float* Wo = (const float*)d_in[5];
    float* out = (float*)d_out;
    hipLaunchKernelGGL(attn_fused, dim3(1024), dim3(256), 0, stream,
                       qf, kf, Wq, Wk, Wv, Wo, out);
}

// Round 2
// 696.632 us; speedup vs baseline: 1.0312x; 1.0312x over previous
//
#include <hip/hip_runtime.h>

// B=2, C=64, D=32, HW=4096; heads=8, hd=8
#define SB   131072          // sites per batch = D*HW
#define CSTR 131072          // channel stride (elements)
#define BSTR 8388608         // batch stride (elements)

using uint4v = __attribute__((ext_vector_type(4))) unsigned int;

__device__ __forceinline__ unsigned short f2bf(float f) {
    unsigned u = __float_as_uint(f);
    u += 0x7fff + ((u >> 16) & 1);   // RNE
    return (unsigned short)(u >> 16);
}
__device__ __forceinline__ unsigned pack2(float a, float b) {
    return (unsigned)f2bf(a) | ((unsigned)f2bf(b) << 16);
}
__device__ __forceinline__ float bflo(unsigned u) { return __uint_as_float(u << 16); }
__device__ __forceinline__ float bfhi(unsigned u) { return __uint_as_float(u & 0xffff0000u); }

// ---------------- K1a: Q projection ----------------
// thread = site; wave covers 64 consecutive sites -> 256B/line loads, 1KB stores
__global__ __launch_bounds__(256)
void k1_q(const float* __restrict__ qf, const float* __restrict__ Wq,
          uint4v* __restrict__ Qs)
{
    const int gid = blockIdx.x * 256 + threadIdx.x;
    const int b = gid >> 17;
    const int t = gid & (SB - 1);
    const float* xp = qf + b * BSTR + t;

    float xr[64];
    #pragma unroll
    for (int c = 0; c < 64; ++c) xr[c] = xp[c * CSTR];

    #pragma unroll 1
    for (int h = 0; h < 8; ++h) {
        float a[8];
        #pragma unroll
        for (int e = 0; e < 8; ++e) {
            float s = 0.f;
            #pragma unroll
            for (int c = 0; c < 64; ++c) s += Wq[(h * 8 + e) * 64 + c] * xr[c];
            a[e] = s;
        }
        uint4v p;
        p.x = pack2(a[0], a[1]); p.y = pack2(a[2], a[3]);
        p.z = pack2(a[4], a[5]); p.w = pack2(a[6], a[7]);
        Qs[(b * 8 + h) * SB + t] = p;
    }
}

// ---------------- K1b: K,V projections ----------------
__global__ __launch_bounds__(256)
void k1_kv(const float* __restrict__ kf, const float* __restrict__ Wk,
           const float* __restrict__ Wv, uint4v* __restrict__ Ks,
           uint4v* __restrict__ Vs)
{
    const int gid = blockIdx.x * 256 + threadIdx.x;
    const int b = gid >> 17;
    const int t = gid & (SB - 1);
    const float* xp = kf + b * BSTR + t;

    float xr[64];
    #pragma unroll
    for (int c = 0; c < 64; ++c) xr[c] = xp[c * CSTR];

    #pragma unroll 1
    for (int h = 0; h < 8; ++h) {
        float ak[8], av[8];
        #pragma unroll
        for (int e = 0; e < 8; ++e) {
            float s0 = 0.f, s1 = 0.f;
            #pragma unroll
            for (int c = 0; c < 64; ++c) {
                s0 += Wk[(h * 8 + e) * 64 + c] * xr[c];
                s1 += Wv[(h * 8 + e) * 64 + c] * xr[c];
            }
            ak[e] = s0; av[e] = s1;
        }
        uint4v pk, pv;
        pk.x = pack2(ak[0], ak[1]); pk.y = pack2(ak[2], ak[3]);
        pk.z = pack2(ak[4], ak[5]); pk.w = pack2(ak[6], ak[7]);
        pv.x = pack2(av[0], av[1]); pv.y = pack2(av[2], av[3]);
        pv.z = pack2(av[4], av[5]); pv.w = pack2(av[6], av[7]);
        Ks[(b * 8 + h) * SB + t] = pk;
        Vs[(b * 8 + h) * SB + t] = pv;
    }
}

// ---------------- K2: attention per (pos-window, head) ----------------
// block = 256 thr = 32 pos x 8 dq-threads (4 rows each). K,V tiles in LDS.
__global__ __launch_bounds__(256)
void k2_attn(const uint4v* __restrict__ Qs, const uint4v* __restrict__ Ks,
             const uint4v* __restrict__ Vs, uint4v* __restrict__ Cs)
{
    __shared__ unsigned int kls[4096];  // [d'][pos] 16B each = 16KB
    __shared__ unsigned int vls[4096];  // 16KB

    const int blk = blockIdx.x;          // 2048 blocks
    const int h   = blk & 7;
    const int w   = blk >> 3;            // 0..255
    const int b   = w >> 7;
    const int pos0 = (w & 127) * 32;

    const int tid = threadIdx.x;
    const int pos = tid & 31;
    const int dqt = tid >> 5;            // 0..7

    const int base = (b * 8 + h) * SB;

    // stage K,V tiles: 1024 x 16B each, fully coalesced
    #pragma unroll
    for (int i = 0; i < 4; ++i) {
        const int idx = tid + i * 256;       // 0..1023
        const int dp = idx >> 5, pp = idx & 31;
        const uint4v kk = Ks[base + dp * 4096 + pos0 + pp];
        const uint4v vv = Vs[base + dp * 4096 + pos0 + pp];
        *(uint4v*)&kls[idx * 4] = kk;
        *(uint4v*)&vls[idx * 4] = vv;
    }
    __syncthreads();

    const float scale = 0.35355339059327373f;  // 8^-0.5

    #pragma unroll 1
    for (int r = 0; r < 4; ++r) {
        const int dq = dqt + 8 * r;
        const uint4v qq = Qs[base + dq * 4096 + pos0 + pos];
        const float q0 = bflo(qq.x), q1 = bfhi(qq.x);
        const float q2 = bflo(qq.y), q3 = bfhi(qq.y);
        const float q4 = bflo(qq.z), q5 = bfhi(qq.z);
        const float q6 = bfhi(qq.w), q7x = 0.f;  // placeholder, fixed below
        (void)q7x;
        const float q6r = bflo(qq.w), q7 = bfhi(qq.w);
        (void)q6;

        float s[32];
        #pragma unroll
        for (int dp = 0; dp < 32; ++dp) {
            const uint4v kk = *(const uint4v*)&kls[(dp * 32 + pos) * 4];
            float acc;
            acc  = q0 * bflo(kk.x);
            acc += q1 * bfhi(kk.x);
            acc += q2 * bflo(kk.y);
            acc += q3 * bfhi(kk.y);
            acc += q4 * bflo(kk.z);
            acc += q5 * bfhi(kk.z);
            acc += q6r * bflo(kk.w);
            acc += q7 * bfhi(kk.w);
            s[dp] = acc * scale;
        }

        float m = s[0];
        #pragma unroll
        for (int dp = 1; dp < 32; ++dp) m = fmaxf(m, s[dp]);
        float sum = 0.f;
        #pragma unroll
        for (int dp = 0; dp < 32; ++dp) { s[dp] = __expf(s[dp] - m); sum += s[dp]; }
        const float inv = 1.0f / sum;

        float cx[8];
        #pragma unroll
        for (int e = 0; e < 8; ++e) cx[e] = 0.f;
        #pragma unroll
        for (int dp = 0; dp < 32; ++dp) {
            const uint4v vv = *(const uint4v*)&vls[(dp * 32 + pos) * 4];
            const float p = s[dp];
            cx[0] += p * bflo(vv.x);
            cx[1] += p * bfhi(vv.x);
            cx[2] += p * bflo(vv.y);
            cx[3] += p * bfhi(vv.y);
            cx[4] += p * bflo(vv.z);
            cx[5] += p * bfhi(vv.z);
            cx[6] += p * bflo(vv.w);
            cx[7] += p * bfhi(vv.w);
        }
        #pragma unroll
        for (int e = 0; e < 8; ++e) cx[e] *= inv;

        uint4v pc;
        pc.x = pack2(cx[0], cx[1]); pc.y = pack2(cx[2], cx[3]);
        pc.z = pack2(cx[4], cx[5]); pc.w = pack2(cx[6], cx[7]);
        Cs[base + dq * 4096 + pos0 + pos] = pc;
    }
}

// ---------------- K3: Wo projection ----------------
__global__ __launch_bounds__(256)
void k3_out(const uint4v* __restrict__ Cs, const float* __restrict__ Wo,
            float* __restrict__ out)
{
    const int gid = blockIdx.x * 256 + threadIdx.x;
    const int b = gid >> 17;
    const int t = gid & (SB - 1);

    float cx[64];
    #pragma unroll
    for (int h = 0; h < 8; ++h) {
        const uint4v u = Cs[(b * 8 + h) * SB + t];
        cx[h * 8 + 0] = bflo(u.x); cx[h * 8 + 1] = bfhi(u.x);
        cx[h * 8 + 2] = bflo(u.y); cx[h * 8 + 3] = bfhi(u.y);
        cx[h * 8 + 4] = bflo(u.z); cx[h * 8 + 5] = bfhi(u.z);
        cx[h * 8 + 6] = bflo(u.w); cx[h * 8 + 7] = bfhi(u.w);
    }

    float* op = out + b * BSTR + t;
    #pragma unroll 1
    for (int g = 0; g < 8; ++g) {
        #pragma unroll
        for (int j = 0; j < 8; ++j) {
            const int o = g * 8 + j;
            float a = 0.f;
            #pragma unroll
            for (int c = 0; c < 64; ++c) a += Wo[o * 64 + c] * cx[c];
            op[o * CSTR] = a;
        }
    }
}

extern "C" void kernel_launch(void* const* d_in, const int* in_sizes, int n_in,
                              void* d_out, int out_size, void* d_ws, size_t ws_size,
                              hipStream_t stream) {
    const float* qf = (const float*)d_in[0];
    const float* kf = (const float*)d_in[1];
    const float* Wq = (const float*)d_in[2];
    const float* Wk = (const float*)d_in[3];
    const float* Wv = (const float*)d_in[4];
    const float* Wo = (const float*)d_in[5];
    float* out = (float*)d_out;

    // scratch layout:
    //   ws:    Q (33.55MB) | ctx (33.55MB)        -> needs 67.1MB
    //   d_out: K (33.55MB) | V (33.55MB)  [bf16]  -> overwritten by K3's fp32 out
    uint4v* Qs = (uint4v*)d_ws;
    uint4v* Cs = (uint4v*)((char*)d_ws + (size_t)33554432);
    uint4v* Ks = (uint4v*)d_out;
    uint4v* Vs = (uint4v*)((char*)d_out + (size_t)33554432);

    hipLaunchKernelGGL(k1_q,  dim3(1024), dim3(256), 0, stream, qf, Wq, Qs);
    hipLaunchKernelGGL(k1_kv, dim3(1024), dim3(256), 0, stream, kf, Wk, Wv, Ks, Vs);
    hipLaunchKernelGGL(k2_attn, dim3(2048), dim3(256), 0, stream, Qs, Ks, Vs, Cs);
    hipLaunchKernelGGL(k3_out, dim3(1024), dim3(256), 0, stream, Cs, Wo, out);
}

// Round 3
// 436.721 us; speedup vs baseline: 1.6449x; 1.5951x over previous
//
#include <hip/hip_runtime.h>

// B=2, C=64, D=32, HW=4096; heads=8, hd=8
#define SB   131072          // sites per batch = D*HW
#define CSTR 131072          // channel stride (elements)
#define BSTR 8388608         // batch stride (elements)

using u32x4  = __attribute__((ext_vector_type(4))) unsigned int;
using u32x2  = __attribute__((ext_vector_type(2))) unsigned int;
using bf16x8 = __attribute__((ext_vector_type(8))) short;   // MFMA A/B frag (4 VGPRs)
using f32x4  = __attribute__((ext_vector_type(4))) float;   // MFMA C/D frag

__device__ __forceinline__ unsigned short f2bf(float f) {
    unsigned u = __float_as_uint(f);
    u += 0x7fff + ((u >> 16) & 1);   // RNE
    return (unsigned short)(u >> 16);
}
__device__ __forceinline__ unsigned pack2(float a, float b) {
    return (unsigned)f2bf(a) | ((unsigned)f2bf(b) << 16);
}
__device__ __forceinline__ float bflo(unsigned u) { return __uint_as_float(u << 16); }
__device__ __forceinline__ float bfhi(unsigned u) { return __uint_as_float(u & 0xffff0000u); }

__device__ __forceinline__ f32x4 mfma16(bf16x8 a, bf16x8 b, f32x4 c) {
    return __builtin_amdgcn_mfma_f32_16x16x32_bf16(a, b, c, 0, 0, 0);
}

// Load 4 mtiles x 2 ktiles of A-fragments from a row-major fp32 [64][64] weight.
// A-frag layout (16x16x32): lane holds A[m = lane&15][k = quad*8 + j], j=0..7.
#define LOAD_A_FRAGS(A, W, n, qd)                                          \
    _Pragma("unroll")                                                      \
    for (int mt = 0; mt < 4; ++mt) {                                       \
        _Pragma("unroll")                                                  \
        for (int kt = 0; kt < 2; ++kt) {                                   \
            union { bf16x8 v; unsigned u[4]; } tw;                         \
            _Pragma("unroll")                                              \
            for (int r = 0; r < 4; ++r) {                                  \
                const int o = mt * 16 + (n);                               \
                const int c = kt * 32 + (qd) * 8 + 2 * r;                  \
                tw.u[r] = pack2(W[o * 64 + c], W[o * 64 + c + 1]);         \
            }                                                              \
            A[mt][kt] = tw.v;                                              \
        }                                                                  \
    }

// ---------------- K1a: Q projection (MFMA) ----------------
// 1024 blocks x 256 thr; wave = 64-site strip = 4 tiles of 16 sites.
__global__ __launch_bounds__(256)
void k1_q(const float* __restrict__ qf, const float* __restrict__ Wq,
          unsigned* __restrict__ Qs)
{
    const int wid  = (blockIdx.x * 256 + threadIdx.x) >> 6;  // 0..4095
    const int lane = threadIdx.x & 63;
    const int qd   = lane >> 4;
    const int n    = lane & 15;
    const int S0   = wid * 64;
    const int b    = S0 >> 17;
    const int tl   = S0 & (SB - 1);
    const float* xb = qf + (size_t)b * BSTR;

    bf16x8 A[4][2];
    LOAD_A_FRAGS(A, Wq, n, qd)

    #pragma unroll
    for (int t = 0; t < 4; ++t) {
        const int site = tl + t * 16 + n;
        // B-frag: B[k=c][n=site]; per-j load = 4x 64B contiguous spans
        bf16x8 Bf[2];
        #pragma unroll
        for (int kt = 0; kt < 2; ++kt) {
            union { bf16x8 v; unsigned u[4]; } tb;
            #pragma unroll
            for (int r = 0; r < 4; ++r) {
                const int c = kt * 32 + qd * 8 + 2 * r;
                tb.u[r] = pack2(xb[(size_t)c * CSTR + site],
                                xb[(size_t)(c + 1) * CSTR + site]);
            }
            Bf[kt] = tb.v;
        }
        f32x4 acc[4];
        #pragma unroll
        for (int mt = 0; mt < 4; ++mt) acc[mt] = (f32x4){0.f, 0.f, 0.f, 0.f};
        #pragma unroll
        for (int kt = 0; kt < 2; ++kt)
            #pragma unroll
            for (int mt = 0; mt < 4; ++mt)
                acc[mt] = mfma16(A[mt][kt], Bf[kt], acc[mt]);
        // store: lane holds out-ch o = mt*16 + qd*4 + r for its site
        // packed record [b][h][site][8e]; quads 0+1 cover 256B densely
        #pragma unroll
        for (int mt = 0; mt < 4; ++mt) {
            const int h = 2 * mt + (qd >> 1);
            unsigned* dst = Qs + ((unsigned)(b * 8 + h) * SB + site) * 4 + (qd & 1) * 2;
            u32x2 w;
            w.x = pack2(acc[mt][0], acc[mt][1]);
            w.y = pack2(acc[mt][2], acc[mt][3]);
            *(u32x2*)dst = w;
        }
    }
}

// ---------------- K1b: K,V projections (MFMA, shared B) ----------------
__global__ __launch_bounds__(256)
void k1_kv(const float* __restrict__ kf, const float* __restrict__ Wk,
           const float* __restrict__ Wv, unsigned* __restrict__ Ks,
           unsigned* __restrict__ Vs)
{
    const int wid  = (blockIdx.x * 256 + threadIdx.x) >> 6;
    const int lane = threadIdx.x & 63;
    const int qd   = lane >> 4;
    const int n    = lane & 15;
    const int S0   = wid * 64;
    const int b    = S0 >> 17;
    const int tl   = S0 & (SB - 1);
    const float* xb = kf + (size_t)b * BSTR;

    bf16x8 AK[4][2], AV[4][2];
    LOAD_A_FRAGS(AK, Wk, n, qd)
    LOAD_A_FRAGS(AV, Wv, n, qd)

    #pragma unroll
    for (int t = 0; t < 4; ++t) {
        const int site = tl + t * 16 + n;
        bf16x8 Bf[2];
        #pragma unroll
        for (int kt = 0; kt < 2; ++kt) {
            union { bf16x8 v; unsigned u[4]; } tb;
            #pragma unroll
            for (int r = 0; r < 4; ++r) {
                const int c = kt * 32 + qd * 8 + 2 * r;
                tb.u[r] = pack2(xb[(size_t)c * CSTR + site],
                                xb[(size_t)(c + 1) * CSTR + site]);
            }
            Bf[kt] = tb.v;
        }
        f32x4 aK[4], aV[4];
        #pragma unroll
        for (int mt = 0; mt < 4; ++mt) {
            aK[mt] = (f32x4){0.f, 0.f, 0.f, 0.f};
            aV[mt] = (f32x4){0.f, 0.f, 0.f, 0.f};
        }
        #pragma unroll
        for (int kt = 0; kt < 2; ++kt)
            #pragma unroll
            for (int mt = 0; mt < 4; ++mt) {
                aK[mt] = mfma16(AK[mt][kt], Bf[kt], aK[mt]);
                aV[mt] = mfma16(AV[mt][kt], Bf[kt], aV[mt]);
            }
        #pragma unroll
        for (int mt = 0; mt < 4; ++mt) {
            const int h = 2 * mt + (qd >> 1);
            const unsigned off = ((unsigned)(b * 8 + h) * SB + site) * 4 + (qd & 1) * 2;
            u32x2 wk2, wv2;
            wk2.x = pack2(aK[mt][0], aK[mt][1]);
            wk2.y = pack2(aK[mt][2], aK[mt][3]);
            wv2.x = pack2(aV[mt][0], aV[mt][1]);
            wv2.y = pack2(aV[mt][2], aV[mt][3]);
            *(u32x2*)(Ks + off) = wk2;
            *(u32x2*)(Vs + off) = wv2;
        }
    }
}

// ---------------- K2: attention per (pos-window, head) ----------------
// block = 256 thr = 32 pos x 8 dq-threads (4 rows each). K,V tiles in LDS.
// NOTE: Cs aliases Qs (each thread reads its Q record before writing ctx to
// the same address; no cross-thread Q sharing) -> no __restrict__ on them.
__global__ __launch_bounds__(256)
void k2_attn(const u32x4* Qs, const u32x4* __restrict__ Ks,
             const u32x4* __restrict__ Vs, u32x4* Cs)
{
    __shared__ unsigned int kls[4096];  // [d'][pos] 16B each = 16KB
    __shared__ unsigned int vls[4096];  // 16KB

    const int blk = blockIdx.x;          // 2048 blocks
    const int h   = blk & 7;
    const int w   = blk >> 3;            // 0..255
    const int b   = w >> 7;
    const int pos0 = (w & 127) * 32;

    const int tid = threadIdx.x;
    const int pos = tid & 31;
    const int dqt = tid >> 5;            // 0..7

    const int base = (b * 8 + h) * SB;

    #pragma unroll
    for (int i = 0; i < 4; ++i) {
        const int idx = tid + i * 256;       // 0..1023
        const int dp = idx >> 5, pp = idx & 31;
        const u32x4 kk = Ks[base + dp * 4096 + pos0 + pp];
        const u32x4 vv = Vs[base + dp * 4096 + pos0 + pp];
        *(u32x4*)&kls[idx * 4] = kk;
        *(u32x4*)&vls[idx * 4] = vv;
    }
    __syncthreads();

    const float scale = 0.35355339059327373f;  // 8^-0.5

    #pragma unroll 1
    for (int r = 0; r < 4; ++r) {
        const int dq = dqt + 8 * r;
        const u32x4 qq = Qs[base + dq * 4096 + pos0 + pos];
        const float q0 = bflo(qq.x), q1 = bfhi(qq.x);
        const float q2 = bflo(qq.y), q3 = bfhi(qq.y);
        const float q4 = bflo(qq.z), q5 = bfhi(qq.z);
        const float q6 = bflo(qq.w), q7 = bfhi(qq.w);

        float s[32];
        #pragma unroll
        for (int dp = 0; dp < 32; ++dp) {
            const u32x4 kk = *(const u32x4*)&kls[(dp * 32 + pos) * 4];
            float acc;
            acc  = q0 * bflo(kk.x);
            acc += q1 * bfhi(kk.x);
            acc += q2 * bflo(kk.y);
            acc += q3 * bfhi(kk.y);
            acc += q4 * bflo(kk.z);
            acc += q5 * bfhi(kk.z);
            acc += q6 * bflo(kk.w);
            acc += q7 * bfhi(kk.w);
            s[dp] = acc * scale;
        }

        float m = s[0];
        #pragma unroll
        for (int dp = 1; dp < 32; ++dp) m = fmaxf(m, s[dp]);
        float sum = 0.f;
        #pragma unroll
        for (int dp = 0; dp < 32; ++dp) { s[dp] = __expf(s[dp] - m); sum += s[dp]; }
        const float inv = 1.0f / sum;

        float cx[8];
        #pragma unroll
        for (int e = 0; e < 8; ++e) cx[e] = 0.f;
        #pragma unroll
        for (int dp = 0; dp < 32; ++dp) {
            const u32x4 vv = *(const u32x4*)&vls[(dp * 32 + pos) * 4];
            const float p = s[dp];
            cx[0] += p * bflo(vv.x);
            cx[1] += p * bfhi(vv.x);
            cx[2] += p * bflo(vv.y);
            cx[3] += p * bfhi(vv.y);
            cx[4] += p * bflo(vv.z);
            cx[5] += p * bfhi(vv.z);
            cx[6] += p * bflo(vv.w);
            cx[7] += p * bfhi(vv.w);
        }
        #pragma unroll
        for (int e = 0; e < 8; ++e) cx[e] *= inv;

        u32x4 pc;
        pc.x = pack2(cx[0], cx[1]); pc.y = pack2(cx[2], cx[3]);
        pc.z = pack2(cx[4], cx[5]); pc.w = pack2(cx[6], cx[7]);
        Cs[base + dq * 4096 + pos0 + pos] = pc;
    }
}

// ---------------- K3: Wo projection (MFMA) ----------------
// B-frag = one dwordx4 ctx record, already bf16 in e-order. No conversion.
__global__ __launch_bounds__(256)
void k3_out(const u32x4* __restrict__ Cs, const float* __restrict__ Wo,
            float* __restrict__ out)
{
    const int wid  = (blockIdx.x * 256 + threadIdx.x) >> 6;
    const int lane = threadIdx.x & 63;
    const int qd   = lane >> 4;
    const int n    = lane & 15;
    const int S0   = wid * 64;
    const int b    = S0 >> 17;
    const int tl   = S0 & (SB - 1);

    bf16x8 A[4][2];
    LOAD_A_FRAGS(A, Wo, n, qd)

    #pragma unroll
    for (int t = 0; t < 4; ++t) {
        const int site = tl + t * 16 + n;
        bf16x8 Bf[2];
        #pragma unroll
        for (int kt = 0; kt < 2; ++kt) {
            // k = kt*32 + qd*8 + j  ->  c = h*8+e with h = kt*4+qd, e = j
            Bf[kt] = *(const bf16x8*)(Cs + (unsigned)(b * 8 + kt * 4 + qd) * SB + site);
        }
        f32x4 acc[4];
        #pragma unroll
        for (int mt = 0; mt < 4; ++mt) acc[mt] = (f32x4){0.f, 0.f, 0.f, 0.f};
        #pragma unroll
        for (int kt = 0; kt < 2; ++kt)
            #pragma unroll
            for (int mt = 0; mt < 4; ++mt)
                acc[mt] = mfma16(A[mt][kt], Bf[kt], acc[mt]);
        #pragma unroll
        for (int mt = 0; mt < 4; ++mt)
            #pragma unroll
            for (int r = 0; r < 4; ++r)
                out[(size_t)b * BSTR + (size_t)(mt * 16 + qd * 4 + r) * CSTR + site]
                    = acc[mt][r];
    }
}

extern "C" void kernel_launch(void* const* d_in, const int* in_sizes, int n_in,
                              void* d_out, int out_size, void* d_ws, size_t ws_size,
                              hipStream_t stream) {
    const float* qf = (const float*)d_in[0];
    const float* kf = (const float*)d_in[1];
    const float* Wq = (const float*)d_in[2];
    const float* Wk = (const float*)d_in[3];
    const float* Wv = (const float*)d_in[4];
    const float* Wo = (const float*)d_in[5];
    float* out = (float*)d_out;

    // scratch layout (bf16 records, 33.55MB each):
    //   ws:    Q (later overwritten in-place by ctx) | V     -> 67.1MB used
    //   d_out: K (33.55MB <= 64MB)  -> overwritten by K3's fp32 out (K dead)
    unsigned* Qs = (unsigned*)d_ws;
    unsigned* Vs = (unsigned*)((char*)d_ws + (size_t)33554432);
    unsigned* Ks = (unsigned*)d_out;

    hipLaunchKernelGGL(k1_q,  dim3(1024), dim3(256), 0, stream, qf, Wq, Qs);
    hipLaunchKernelGGL(k1_kv, dim3(1024), dim3(256), 0, stream, kf, Wk, Wv, Ks, Vs);
    hipLaunchKernelGGL(k2_attn, dim3(2048), dim3(256), 0, stream,
                       (const u32x4*)Qs, (const u32x4*)Ks, (const u32x4*)Vs,
                       (u32x4*)Qs);
    hipLaunchKernelGGL(k3_out, dim3(1024), dim3(256), 0, stream,
                       (const u32x4*)Qs, Wo, out);
}